// Round 23
// baseline (372.143 us; speedup 1.0000x reference)
//
#include <hip/hip_runtime.h>
#include <math.h>

#define N_PTS 16384
#define BATCH 2
#define CIN   32
#define H_DIM 128
#define COUT  64
#define KNN   16
#define GC    24                  // grid cells per dim (r23: radius ~1.5 cells)
#define NCELL (GC * GC * GC)      // 13824
#define CS    (1.0f / GC)
#define CPT   14                  // cells per scan thread (1024*14 >= NCELL)
#define PB    4                   // points per MLP block
#define CHUNK 2048

typedef unsigned short ushortT;

__device__ __forceinline__ float gelu_f(float x) {
    float x3 = x * x * x;
    float t  = tanhf(0.7978845608028654f * (x + 0.044715f * x3));
    return 0.5f * x * (1.0f + t);
}
__device__ __forceinline__ float gelu_fast(float x) {
    float z = 1.5957691216057308f * (x + 0.044715f * x * x * x);
    return x / (1.0f + __expf(-z));
}

__device__ __forceinline__ int cellco(float v) {
    int c = (int)(v * (float)GC);
    return c < 0 ? 0 : (c > GC - 1 ? GC - 1 : c);
}

// ---------------- bucket build ----------------
__global__ __launch_bounds__(256)
void zero_kernel(int* __restrict__ cnt) {
    cnt[blockIdx.x * 256 + threadIdx.x] = 0;   // grid = BATCH*NCELL/256 = 108
}

__global__ __launch_bounds__(256)
void count_kernel(const float* __restrict__ pos, int* __restrict__ cnt) {
    const int t = blockIdx.x * 256 + threadIdx.x;
    const int b = t >> 14;
    float x = pos[(size_t)t * 3 + 0];
    float y = pos[(size_t)t * 3 + 1];
    float z = pos[(size_t)t * 3 + 2];
    int cell = (cellco(z) * GC + cellco(y)) * GC + cellco(x);
    atomicAdd(&cnt[b * NCELL + cell], 1);
}

// prefix-scan over NCELL cells: 1024 threads x CPT cells each (bounds-checked)
__global__ __launch_bounds__(1024)
void scan_kernel(const int* __restrict__ cnt, int* __restrict__ off,
                 int* __restrict__ cur) {
    __shared__ int s[1024];
    const int b = blockIdx.x;
    const int t = threadIdx.x;
    const int* c = cnt + b * NCELL;
    const int base = t * CPT;
    int tot = 0;
    for (int i = 0; i < CPT; ++i) {
        int idx = base + i;
        if (idx < NCELL) tot += c[idx];
    }
    s[t] = tot;
    __syncthreads();
    for (int d = 1; d < 1024; d <<= 1) {
        int add = (t >= d) ? s[t - d] : 0;
        __syncthreads();
        s[t] += add;
        __syncthreads();
    }
    int run = s[t] - tot;          // exclusive prefix of this thread's chunk
    int* ob = off + b * (NCELL + 1);
    int* cb = cur + b * NCELL;
    for (int i = 0; i < CPT; ++i) {
        int idx = base + i;
        if (idx < NCELL) {
            ob[idx] = run;
            cb[idx] = run;
            run += c[idx];
        }
    }
    if (t == 1023) ob[NCELL] = run;   // == N_PTS
}

// scatter: also record slot_of[pid] (inverse permutation) for the MLP
__global__ __launch_bounds__(256)
void scatter_kernel(const float* __restrict__ pos, int* __restrict__ cur,
                    float4* __restrict__ pos4, ushortT* __restrict__ slot_of) {
    const int t = blockIdx.x * 256 + threadIdx.x;
    const int b = t >> 14;
    const int pid = t & (N_PTS - 1);
    float x = pos[(size_t)t * 3 + 0];
    float y = pos[(size_t)t * 3 + 1];
    float z = pos[(size_t)t * 3 + 2];
    int cell = (cellco(z) * GC + cellco(y)) * GC + cellco(x);
    int slot = atomicAdd(&cur[b * NCELL + cell], 1);
    pos4[(size_t)b * N_PTS + slot] = make_float4(x, y, z, __int_as_float(pid));
    slot_of[(size_t)b * N_PTS + pid] = (ushortT)slot;
}

// ---- KNN: r22 exact scan + cell-bound pruning, GC=24.  Pruned rows never
// touch offb (prune check is pure VALU).  Global offb reads (soff cache was
// proven neutral in r17; a GC=24 table would not fit LDS cheaply).  Exact
// top-16 is grid-independent: same comparator, same _rn distances, same
// conservative bounds -> bit-identical output to rounds 10-22.
__global__ __launch_bounds__(64)
void knnq_kernel(const float4* __restrict__ pos4,
                 const int* __restrict__ off, ushortT* __restrict__ out_idx) {
    const int tid = threadIdx.x;
    const int t = blockIdx.x * 64 + tid;            // slot id, 0..32767
    const int b = t >> 14;
    const float4 Q = pos4[t];                       // coalesced
    const float qx = Q.x, qy = Q.y, qz = Q.z;
    const int pid = __float_as_int(Q.w);
    const int cx = cellco(qx), cy = cellco(qy), cz = cellco(qz);
    const float4* p4b = pos4 + (size_t)b * N_PTS;
    const int* offb = off + b * (NCELL + 1);

    float ld[KNN]; int li[KNN];
#pragma unroll
    for (int p = 0; p < KNN; ++p) { ld[p] = 3.0e38f; li[p] = 0x7fffffff; }
    float t15d = 3.0e38f; int t15i = 0x7fffffff;

    // min |q - cellcoord| along one axis for cell index X (cell = [X*CS,(X+1)*CS))
    auto axmind = [&](int X, float q) {
        float dl = (float)X * CS - q;
        float dh = q - (float)(X + 1) * CS;
        return fmaxf(0.f, fmaxf(dl, dh));
    };

    // scan a contiguous slot range [s,e) with 8-wide batched loads
    auto scan_range = [&](int s, int e2) {
        for (int u = s; u < e2; u += 8) {
            float4 pg[8];
#pragma unroll
            for (int i = 0; i < 8; ++i) {
                int uu = u + i; uu = uu < e2 - 1 ? uu : e2 - 1;   // clamp
                pg[i] = p4b[uu];
            }
#pragma unroll
            for (int i = 0; i < 8; ++i) {
                if (u + i >= e2) break;
                // exact numpy op order: (dx*dx + dy*dy) + dz*dz, no FMA
                float ddx = __fsub_rn(qx, pg[i].x);
                float ddy = __fsub_rn(qy, pg[i].y);
                float ddz = __fsub_rn(qz, pg[i].z);
                float d = __fadd_rn(__fadd_rn(__fmul_rn(ddx, ddx),
                                              __fmul_rn(ddy, ddy)),
                                    __fmul_rn(ddz, ddz));
                int pj = __float_as_int(pg[i].w);
                if (d < t15d || (d == t15d && pj < t15i)) {
                    float cd = d; int cj = pj;
#pragma unroll
                    for (int p = 0; p < KNN; ++p) {
                        bool sw = (cd < ld[p]) || (cd == ld[p] && cj < li[p]);
                        float td = ld[p]; int ti = li[p];
                        ld[p] = sw ? cd : td; li[p] = sw ? cj : ti;
                        cd = sw ? td : cd;    cj = sw ? ti : cj;
                    }
                    t15d = ld[KNN - 1]; t15i = li[KNN - 1];
                }
            }
        }
    };

    for (int r = 1; r <= GC; ++r) {
        for (int dz = -r; dz <= r; ++dz) {
            const int Z = cz + dz; if ((unsigned)Z >= GC) continue;
            const float fz = axmind(Z, qz);
            for (int dy = -r; dy <= r; ++dy) {
                const int Y = cy + dy; if ((unsigned)Y >= GC) continue;
                const float fy = axmind(Y, qy);
                const float base2 = fy * fy + fz * fz;
                if (base2 * 0.99999f > t15d) continue;   // row provably empty of top-16
                const int rowbase = (Z * GC + Y) * GC;
                const bool fullrow = (r == 1) ||
                    (dz == -r || dz == r || dy == -r || dy == r);
                if (fullrow) {
                    int X0 = cx - r; X0 = X0 < 0 ? 0 : X0;
                    int X1 = cx + r; X1 = X1 > GC - 1 ? GC - 1 : X1;
                    while (X0 < cx) {
                        float fx = axmind(X0, qx);
                        if ((base2 + fx * fx) * 0.99999f > t15d) ++X0; else break;
                    }
                    while (X1 > cx) {
                        float fx = axmind(X1, qx);
                        if ((base2 + fx * fx) * 0.99999f > t15d) --X1; else break;
                    }
                    scan_range(offb[rowbase + X0], offb[rowbase + X1 + 1]);
                } else {
                    const int Xl = cx - r, Xr = cx + r;
                    if (Xl >= 0) {
                        float fx = axmind(Xl, qx);
                        if ((base2 + fx * fx) * 0.99999f <= t15d)
                            scan_range(offb[rowbase + Xl], offb[rowbase + Xl + 1]);
                    }
                    if (Xr <= GC - 1) {
                        float fx = axmind(Xr, qx);
                        if ((base2 + fx * fx) * 0.99999f <= t15d)
                            scan_range(offb[rowbase + Xr], offb[rowbase + Xr + 1]);
                    }
                }
            }
        }
        // conservative termination: any unprocessed point has d^2 >= margin^2
        float mg = 1.0e19f;   // clipped faces -> nothing beyond
        if (cx - r > 0)      mg = fminf(mg, qx - (float)(cx - r) * CS);
        if (cx + r < GC - 1) mg = fminf(mg, (float)(cx + r + 1) * CS - qx);
        if (cy - r > 0)      mg = fminf(mg, qy - (float)(cy - r) * CS);
        if (cy + r < GC - 1) mg = fminf(mg, (float)(cy + r + 1) * CS - qy);
        if (cz - r > 0)      mg = fminf(mg, qz - (float)(cz - r) * CS);
        if (cz + r < GC - 1) mg = fminf(mg, (float)(cz + r + 1) * CS - qz);
        if (t15d < mg * mg * 0.99999f) break;
    }
    ushortT* dst = out_idx + ((size_t)(b << 14) + pid) * KNN;
#pragma unroll
    for (int p = 0; p < KNN; ++p) dst[p] = (ushortT)li[p];
}

// ------- feat1s: SLOT-ordered feat1.  Row s = F[pid(s)] @ W1[0:CIN]. -------
__global__ __launch_bounds__(256)
void feat1s_kernel(const float4* __restrict__ pos4, const float* __restrict__ feats,
                   const float* __restrict__ W1, float* __restrict__ feat1s) {
    const int g = blockIdx.x * 256 + threadIdx.x;    // over M*H_DIM
    const int s = g >> 7;                            // global slot
    const int h = g & 127;
    const int b = s >> 14;
    const int pid = __float_as_int(pos4[s].w);
    const float* fr = feats + ((size_t)b * N_PTS + pid) * CIN;
    float a = 0.f;
#pragma unroll
    for (int c = 0; c < CIN; ++c)
        a += fr[c] * W1[c * H_DIM + h];
    feat1s[(size_t)s * H_DIM + h] = a;
}

// ---- MLP v2s: 4 consecutive SLOTS per block (r21/r22 proven). ----
__global__ __launch_bounds__(64)
void mlp2s_kernel(const float4* __restrict__ pos4, const float* __restrict__ feats,
                  const ushortT* __restrict__ knn_idx, const ushortT* __restrict__ slot_of,
                  const float* __restrict__ feat1s,
                  const float* __restrict__ W1, const float* __restrict__ b1,
                  const float* __restrict__ W2, const float* __restrict__ b2,
                  const float* __restrict__ W3, const float* __restrict__ b3,
                  const float* __restrict__ W4, const float* __restrict__ b4,
                  float* __restrict__ out) {
    __shared__ ushortT sIdx[PB][KNN];         // neighbor SLOTS
    __shared__ int   spid[PB];                // own pids
    __shared__ float sq[PB][3];
    __shared__ __align__(16) float fself[PB][CIN];
    __shared__ float npx[PB][KNN][3];
    __shared__ __align__(16) float gs[PB][H_DIM];
    __shared__ __align__(16) float aggs[PB][COUT];
    __shared__ __align__(16) float hs[PB][H_DIM];

    const int tid = threadIdx.x;            // 0..63
    const int h0 = tid, h1 = tid + 64;
    const int i0 = blockIdx.x * PB;         // global slot base
    const int b  = i0 >> 14;
    const size_t bofs = (size_t)b * N_PTS;

    if (tid < PB) {
        float4 P = pos4[i0 + tid];
        sq[tid][0] = P.x; sq[tid][1] = P.y; sq[tid][2] = P.z;
        spid[tid] = __float_as_int(P.w);
    }
    __syncthreads();     // spid/sq ready
    for (int e = tid; e < PB * KNN; e += 64) {
        int p = e >> 4, k = e & 15;
        int npid = knn_idx[(bofs + spid[p]) * KNN + k];
        sIdx[p][k] = slot_of[bofs + npid];
    }
    for (int e = tid; e < PB * CIN; e += 64)
        fself[e >> 5][e & 31] = feats[(bofs + spid[e >> 5]) * CIN + (e & 31)];
    __syncthreads();     // sIdx ready
    for (int e = tid; e < PB * KNN; e += 64) {
        int p = e >> 4, k = e & 15;
        float4 P = pos4[bofs + sIdx[p][k]];
        npx[p][k][0] = P.x; npx[p][k][1] = P.y; npx[p][k][2] = P.z;
    }

    const float w0A = W1[(2 * CIN + 0) * H_DIM + h0], w0B = W1[(2 * CIN + 0) * H_DIM + h1];
    const float w1A = W1[(2 * CIN + 1) * H_DIM + h0], w1B = W1[(2 * CIN + 1) * H_DIM + h1];
    const float w2A = W1[(2 * CIN + 2) * H_DIM + h0], w2B = W1[(2 * CIN + 2) * H_DIM + h1];
    float bA[PB], bB[PB];
#pragma unroll
    for (int p = 0; p < PB; ++p) { bA[p] = b1[h0]; bB[p] = b1[h1]; }
    __syncthreads();   // npx/fself ready
#pragma unroll
    for (int c = 0; c < CIN; ++c) {
        float wA = W1[(CIN + c) * H_DIM + h0];
        float wB = W1[(CIN + c) * H_DIM + h1];
#pragma unroll
        for (int p = 0; p < PB; ++p) {
            bA[p] += fself[p][c] * wA;
            bB[p] += fself[p][c] * wB;
        }
    }

    float accA[PB] = {0.f, 0.f, 0.f, 0.f};
    float accB[PB] = {0.f, 0.f, 0.f, 0.f};
    for (int k = 0; k < KNN; ++k) {
#pragma unroll
        for (int p = 0; p < PB; ++p) {
            const float* fr = feat1s + ((size_t)bofs + sIdx[p][k]) * H_DIM;
            float rx = npx[p][k][0] - sq[p][0];
            float ry = npx[p][k][1] - sq[p][1];
            float rz = npx[p][k][2] - sq[p][2];
            float uA = bA[p] + fr[h0] + rx * w0A + ry * w1A + rz * w2A;
            float uB = bB[p] + fr[h1] + rx * w0B + ry * w1B + rz * w2B;
            accA[p] += gelu_fast(uA);
            accB[p] += gelu_fast(uB);
        }
    }
#pragma unroll
    for (int p = 0; p < PB; ++p) {
        gs[p][h0] = accA[p] * (1.0f / KNN);
        gs[p][h1] = accB[p] * (1.0f / KNN);
    }
    __syncthreads();

    float a2[PB];
#pragma unroll
    for (int p = 0; p < PB; ++p) a2[p] = b2[h0];
    for (int c4 = 0; c4 < H_DIM / 4; ++c4) {
        float wx = W2[(4 * c4 + 0) * COUT + h0];
        float wy = W2[(4 * c4 + 1) * COUT + h0];
        float wz = W2[(4 * c4 + 2) * COUT + h0];
        float ww = W2[(4 * c4 + 3) * COUT + h0];
#pragma unroll
        for (int p = 0; p < PB; ++p) {
            float4 g = ((const float4*)gs[p])[c4];
            a2[p] += g.x * wx + g.y * wy + g.z * wz + g.w * ww;
        }
    }
#pragma unroll
    for (int p = 0; p < PB; ++p) aggs[p][h0] = a2[p];
    __syncthreads();

    float a3A[PB], a3B[PB];
#pragma unroll
    for (int p = 0; p < PB; ++p) { a3A[p] = b3[h0]; a3B[p] = b3[h1]; }
    for (int c4 = 0; c4 < COUT / 4; ++c4) {
        float wxA = W3[(4 * c4 + 0) * H_DIM + h0], wxB = W3[(4 * c4 + 0) * H_DIM + h1];
        float wyA = W3[(4 * c4 + 1) * H_DIM + h0], wyB = W3[(4 * c4 + 1) * H_DIM + h1];
        float wzA = W3[(4 * c4 + 2) * H_DIM + h0], wzB = W3[(4 * c4 + 2) * H_DIM + h1];
        float wwA = W3[(4 * c4 + 3) * H_DIM + h0], wwB = W3[(4 * c4 + 3) * H_DIM + h1];
#pragma unroll
        for (int p = 0; p < PB; ++p) {
            float4 g = ((const float4*)aggs[p])[c4];
            a3A[p] += g.x * wxA + g.y * wyA + g.z * wzA + g.w * wwA;
            a3B[p] += g.x * wxB + g.y * wyB + g.z * wzB + g.w * wwB;
        }
    }
#pragma unroll
    for (int p = 0; p < PB; ++p) {
        hs[p][h0] = gelu_fast(a3A[p]);
        hs[p][h1] = gelu_fast(a3B[p]);
    }
    __syncthreads();

    float o4[PB];
#pragma unroll
    for (int p = 0; p < PB; ++p) o4[p] = b4[h0];
    for (int c4 = 0; c4 < H_DIM / 4; ++c4) {
        float wx = W4[(4 * c4 + 0) * COUT + h0];
        float wy = W4[(4 * c4 + 1) * COUT + h0];
        float wz = W4[(4 * c4 + 2) * COUT + h0];
        float ww = W4[(4 * c4 + 3) * COUT + h0];
#pragma unroll
        for (int p = 0; p < PB; ++p) {
            float4 v = ((const float4*)hs[p])[c4];
            o4[p] += v.x * wx + v.y * wy + v.z * wz + v.w * ww;
        }
    }
#pragma unroll
    for (int p = 0; p < PB; ++p)
        out[((size_t)bofs + spid[p]) * COUT + h0] = o4[p];
}

// ---------- MLP v1 (round-8, proven): used when ws too small for feat1 -------
__global__ __launch_bounds__(64)
void mlp_kernel(const float* __restrict__ pos, const float* __restrict__ feats,
                const ushortT* __restrict__ knn_idx,
                const float* __restrict__ W1, const float* __restrict__ b1,
                const float* __restrict__ W2, const float* __restrict__ b2,
                const float* __restrict__ W3, const float* __restrict__ b3,
                const float* __restrict__ W4, const float* __restrict__ b4,
                float* __restrict__ out) {
    __shared__ ushortT sIdx[PB][KNN];
    __shared__ float sq[PB][3];
    __shared__ __align__(16) float fself[PB][CIN];
    __shared__ float npx[PB][KNN][3];
    __shared__ __align__(16) float nf[PB][KNN][CIN];
    __shared__ __align__(16) float gs[PB][H_DIM];
    __shared__ __align__(16) float aggs[PB][COUT];
    __shared__ __align__(16) float hs[PB][H_DIM];

    const int tid = threadIdx.x;
    const int h0 = tid, h1 = tid + 64;
    const int i0 = blockIdx.x * PB;
    const size_t bofs = (size_t)(i0 >> 14) * N_PTS;

    for (int e = tid; e < PB * KNN; e += 64)
        sIdx[e >> 4][e & 15] = knn_idx[(size_t)(i0 + (e >> 4)) * KNN + (e & 15)];
    for (int e = tid; e < PB * 3; e += 64)
        sq[e / 3][e % 3] = pos[(size_t)(i0 + e / 3) * 3 + (e % 3)];
    for (int e = tid; e < PB * CIN; e += 64)
        fself[e >> 5][e & 31] = feats[(size_t)(i0 + (e >> 5)) * CIN + (e & 31)];
    __syncthreads();
    for (int e = tid; e < PB * KNN * CIN; e += 64) {
        int p = e >> 9, k = (e >> 5) & 15, c = e & 31;
        nf[p][k][c] = feats[(bofs + sIdx[p][k]) * CIN + c];
    }
    for (int e = tid; e < PB * KNN * 3; e += 64) {
        int p = e / (KNN * 3), r = e % (KNN * 3), k = r / 3, c = r % 3;
        npx[p][k][c] = pos[(bofs + sIdx[p][k]) * 3 + c];
    }

    float w1rA[CIN], w1rB[CIN];
#pragma unroll
    for (int c = 0; c < CIN; ++c) {
        w1rA[c] = W1[c * H_DIM + h0];
        w1rB[c] = W1[c * H_DIM + h1];
    }
    const float w0A = W1[(2 * CIN + 0) * H_DIM + h0], w0B = W1[(2 * CIN + 0) * H_DIM + h1];
    const float w1A = W1[(2 * CIN + 1) * H_DIM + h0], w1B = W1[(2 * CIN + 1) * H_DIM + h1];
    const float w2A = W1[(2 * CIN + 2) * H_DIM + h0], w2B = W1[(2 * CIN + 2) * H_DIM + h1];
    float bA[PB], bB[PB];
#pragma unroll
    for (int p = 0; p < PB; ++p) { bA[p] = b1[h0]; bB[p] = b1[h1]; }
    __syncthreads();
#pragma unroll
    for (int c = 0; c < CIN; ++c) {
        float wA = W1[(CIN + c) * H_DIM + h0];
        float wB = W1[(CIN + c) * H_DIM + h1];
#pragma unroll
        for (int p = 0; p < PB; ++p) {
            bA[p] += fself[p][c] * wA;
            bB[p] += fself[p][c] * wB;
        }
    }

    float accA[PB] = {0.f, 0.f, 0.f, 0.f};
    float accB[PB] = {0.f, 0.f, 0.f, 0.f};
    for (int k = 0; k < KNN; ++k) {
#pragma unroll
        for (int p = 0; p < PB; ++p) {
            float rx = npx[p][k][0] - sq[p][0];
            float ry = npx[p][k][1] - sq[p][1];
            float rz = npx[p][k][2] - sq[p][2];
            float uA = bA[p] + rx * w0A + ry * w1A + rz * w2A;
            float uB = bB[p] + rx * w0B + ry * w1B + rz * w2B;
            const float4* nf4 = (const float4*)nf[p][k];
#pragma unroll
            for (int c4 = 0; c4 < CIN / 4; ++c4) {
                float4 v = nf4[c4];
                uA += v.x * w1rA[4 * c4] + v.y * w1rA[4 * c4 + 1]
                    + v.z * w1rA[4 * c4 + 2] + v.w * w1rA[4 * c4 + 3];
                uB += v.x * w1rB[4 * c4] + v.y * w1rB[4 * c4 + 1]
                    + v.z * w1rB[4 * c4 + 2] + v.w * w1rB[4 * c4 + 3];
            }
            accA[p] += gelu_f(uA);
            accB[p] += gelu_f(uB);
        }
    }
#pragma unroll
    for (int p = 0; p < PB; ++p) {
        gs[p][h0] = accA[p] * (1.0f / KNN);
        gs[p][h1] = accB[p] * (1.0f / KNN);
    }
    __syncthreads();

    float a2[PB];
#pragma unroll
    for (int p = 0; p < PB; ++p) a2[p] = b2[h0];
    for (int c4 = 0; c4 < H_DIM / 4; ++c4) {
        float wx = W2[(4 * c4 + 0) * COUT + h0];
        float wy = W2[(4 * c4 + 1) * COUT + h0];
        float wz = W2[(4 * c4 + 2) * COUT + h0];
        float ww = W2[(4 * c4 + 3) * COUT + h0];
#pragma unroll
        for (int p = 0; p < PB; ++p) {
            float4 g = ((const float4*)gs[p])[c4];
            a2[p] += g.x * wx + g.y * wy + g.z * wz + g.w * ww;
        }
    }
#pragma unroll
    for (int p = 0; p < PB; ++p) aggs[p][h0] = a2[p];
    __syncthreads();

    float a3A[PB], a3B[PB];
#pragma unroll
    for (int p = 0; p < PB; ++p) { a3A[p] = b3[h0]; a3B[p] = b3[h1]; }
    for (int c4 = 0; c4 < COUT / 4; ++c4) {
        float wxA = W3[(4 * c4 + 0) * H_DIM + h0], wxB = W3[(4 * c4 + 0) * H_DIM + h1];
        float wyA = W3[(4 * c4 + 1) * H_DIM + h0], wyB = W3[(4 * c4 + 1) * H_DIM + h1];
        float wzA = W3[(4 * c4 + 2) * H_DIM + h0], wzB = W3[(4 * c4 + 2) * H_DIM + h1];
        float wwA = W3[(4 * c4 + 3) * H_DIM + h0], wwB = W3[(4 * c4 + 3) * H_DIM + h1];
#pragma unroll
        for (int p = 0; p < PB; ++p) {
            float4 g = ((const float4*)aggs[p])[c4];
            a3A[p] += g.x * wxA + g.y * wyA + g.z * wzA + g.w * wwA;
            a3B[p] += g.x * wxB + g.y * wyB + g.z * wzB + g.w * wwB;
        }
    }
#pragma unroll
    for (int p = 0; p < PB; ++p) {
        hs[p][h0] = gelu_f(a3A[p]);
        hs[p][h1] = gelu_f(a3B[p]);
    }
    __syncthreads();

    float o4[PB];
#pragma unroll
    for (int p = 0; p < PB; ++p) o4[p] = b4[h0];
    for (int c4 = 0; c4 < H_DIM / 4; ++c4) {
        float wx = W4[(4 * c4 + 0) * COUT + h0];
        float wy = W4[(4 * c4 + 1) * COUT + h0];
        float wz = W4[(4 * c4 + 2) * COUT + h0];
        float ww = W4[(4 * c4 + 3) * COUT + h0];
#pragma unroll
        for (int p = 0; p < PB; ++p) {
            float4 v = ((const float4*)hs[p])[c4];
            o4[p] += v.x * wx + v.y * wy + v.z * wz + v.w * ww;
        }
    }
#pragma unroll
    for (int p = 0; p < PB; ++p)
        out[(size_t)(i0 + p) * COUT + h0] = o4[p];
}

// =============== FALLBACK: round-6 fused kernel (proven passing) =============
#define NT    128
#define LP    17
__global__ __launch_bounds__(NT)
void fused_kernel(const float* __restrict__ pos, const float* __restrict__ feats,
                  const float* __restrict__ W1, const float* __restrict__ b1,
                  const float* __restrict__ W2, const float* __restrict__ b2,
                  const float* __restrict__ W3, const float* __restrict__ b3,
                  const float* __restrict__ W4, const float* __restrict__ b4,
                  float* __restrict__ out) {
    __shared__ float sx[CHUNK], sy[CHUNK], sz[CHUNK];
    __shared__ float ld0[NT * LP]; __shared__ int li0[NT * LP];
    __shared__ float ld1[NT * LP]; __shared__ int li1[NT * LP];
    __shared__ int   sIdx[KNN];
    __shared__ float npx[KNN][3];
    __shared__ float nf[KNN][CIN];
    __shared__ float fself[CIN];
    __shared__ float gs[H_DIM];
    __shared__ float aggs[COUT];
    __shared__ float hs[H_DIM];

    const int i   = blockIdx.x;
    const int b   = i >> 14;
    const int tid = threadIdx.x;
    const float* posb = pos + (size_t)b * N_PTS * 3;

    const float qx = pos[(size_t)i * 3 + 0];
    const float qy = pos[(size_t)i * 3 + 1];
    const float qz = pos[(size_t)i * 3 + 2];

    const int base = tid * LP;
    for (int s = 0; s < KNN; ++s) { ld0[base + s] = 3.0e38f; li0[base + s] = 0x7fffffff; }
    float taild = 3.0e38f;

    for (int cbase = 0; cbase < N_PTS; cbase += CHUNK) {
        __syncthreads();
        for (int t = tid; t < CHUNK * 3; t += NT) {
            float v = posb[(size_t)cbase * 3 + t];
            int c = t % 3, r = t / 3;
            (c == 0 ? sx : (c == 1 ? sy : sz))[r] = v;
        }
        __syncthreads();
        for (int r = tid; r < CHUNK; r += NT) {
            float dx = __fsub_rn(qx, sx[r]);
            float dy = __fsub_rn(qy, sy[r]);
            float dz = __fsub_rn(qz, sz[r]);
            float d  = __fadd_rn(__fadd_rn(__fmul_rn(dx, dx), __fmul_rn(dy, dy)),
                                 __fmul_rn(dz, dz));
            const int j = cbase + r;
            if (d < taild) {
                int p = KNN - 1;
                while (p > 0) {
                    float pd = ld0[base + p - 1];
                    if (!(pd > d)) break;
                    ld0[base + p] = pd;
                    li0[base + p] = li0[base + p - 1];
                    --p;
                }
                ld0[base + p] = d;
                li0[base + p] = j;
                taild = ld0[base + KNN - 1];
            }
        }
    }

    int cur = 0;
    for (int s = 1; s < NT; s <<= 1) {
        __syncthreads();
        if ((tid & (2 * s - 1)) == 0) {
            const float* cd  = cur ? ld1 : ld0;
            const int*   cix = cur ? li1 : li0;
            float* nd  = cur ? ld0 : ld1;
            int*   nix = cur ? li0 : li1;
            const int A = tid * LP, B = (tid + s) * LP, O = tid * LP;
            int a = 0, bb = 0;
            for (int o = 0; o < KNN; ++o) {
                float da = cd[A + a], db = cd[B + bb];
                int   ia = cix[A + a], ib = cix[B + bb];
                bool tA = (da < db) || (da == db && ia < ib);
                nd[O + o]  = tA ? da : db;
                nix[O + o] = tA ? ia : ib;
                a += tA ? 1 : 0; bb += tA ? 0 : 1;
            }
        }
        cur ^= 1;
    }
    __syncthreads();
    {
        const int* fli = cur ? li1 : li0;
        if (tid < KNN) sIdx[tid] = fli[tid];
        if (tid < CIN) fself[tid] = feats[(size_t)i * CIN + tid];
    }
    __syncthreads();

    for (int e = tid; e < KNN * CIN; e += NT) {
        int k = e >> 5, c = e & 31;
        nf[k][c] = feats[((size_t)b * N_PTS + sIdx[k]) * CIN + c];
    }
    if (tid < KNN * 3) {
        int k = tid / 3, c = tid % 3;
        npx[k][c] = posb[sIdx[k] * 3 + c];
    }
    const int h = tid;
    float w1r[CIN];
#pragma unroll
    for (int c = 0; c < CIN; ++c) w1r[c] = W1[c * H_DIM + h];
    float baseh = b1[h];
    const float w0 = W1[(2 * CIN + 0) * H_DIM + h];
    const float w1 = W1[(2 * CIN + 1) * H_DIM + h];
    const float w2 = W1[(2 * CIN + 2) * H_DIM + h];
#pragma unroll
    for (int c = 0; c < CIN; ++c)
        baseh += fself[c] * W1[(CIN + c) * H_DIM + h];
    __syncthreads();

    float acc = 0.f;
    for (int k = 0; k < KNN; ++k) {
        float u = baseh
                + (npx[k][0] - qx) * w0
                + (npx[k][1] - qy) * w1
                + (npx[k][2] - qz) * w2;
#pragma unroll
        for (int c = 0; c < CIN; ++c)
            u += nf[k][c] * w1r[c];
        acc += gelu_f(u);
    }
    gs[h] = acc * (1.0f / KNN);
    __syncthreads();

    if (h < COUT) {
        float a = b2[h];
#pragma unroll
        for (int t2 = 0; t2 < H_DIM; ++t2)
            a += gs[t2] * W2[t2 * COUT + h];
        aggs[h] = a;
    }
    __syncthreads();

    float a3 = b3[h];
#pragma unroll
    for (int c = 0; c < COUT; ++c)
        a3 += aggs[c] * W3[c * H_DIM + h];
    hs[h] = gelu_f(a3);
    __syncthreads();
    if (h < COUT) {
        float o = b4[h];
#pragma unroll
        for (int t2 = 0; t2 < H_DIM; ++t2)
            o += hs[t2] * W4[t2 * COUT + h];
        out[(size_t)i * COUT + h] = o;
    }
}

extern "C" void kernel_launch(void* const* d_in, const int* in_sizes, int n_in,
                              void* d_out, int out_size, void* d_ws, size_t ws_size,
                              hipStream_t stream) {
    const float* pos   = (const float*)d_in[0];
    const float* feats = (const float*)d_in[1];
    const float* W1    = (const float*)d_in[2];
    const float* b1    = (const float*)d_in[3];
    const float* W2    = (const float*)d_in[4];
    const float* b2    = (const float*)d_in[5];
    const float* W3    = (const float*)d_in[6];
    const float* b3    = (const float*)d_in[7];
    const float* W4    = (const float*)d_in[8];
    const float* b4    = (const float*)d_in[9];
    float* out = (float*)d_out;

    const int M = BATCH * N_PTS;   // 32768

    // ws layout (GC=24):
    //   [0,1MB)        idx     ushort [32768*16]
    //   [1MB,1.5MB)    pos4    float4 [32768]
    //   cnt            int [2*13824]
    //   off            int [2*13825]
    //   cur            int [2*13824]
    //   slot_of        ushort [32768]
    //   [2MB,18MB)     feat1s  f32 [32768*128]   (only if ws >= 18MB)
    char* ws = (char*)d_ws;
    const size_t cnt_ofs   = (size_t)1536 * 1024;
    const size_t off_ofs   = cnt_ofs + (size_t)BATCH * NCELL * 4;
    const size_t cur_ofs   = off_ofs + (size_t)BATCH * (NCELL + 1) * 4;
    const size_t slot_ofs  = cur_ofs + (size_t)BATCH * NCELL * 4;
    const size_t need_small = slot_ofs + (size_t)M * 2;
    const size_t feat1_ofs  = (size_t)2 * 1024 * 1024;
    const size_t need_big   = (size_t)18 * 1024 * 1024;

    if (ws_size >= need_small && need_small <= feat1_ofs && d_ws != nullptr) {
        ushortT* idx   = (ushortT*)ws;
        float4*  pos4  = (float4*)(ws + (size_t)1024 * 1024);
        int*     cnt   = (int*)(ws + cnt_ofs);
        int*     off   = (int*)(ws + off_ofs);
        int*     curp  = (int*)(ws + cur_ofs);
        ushortT* slotf = (ushortT*)(ws + slot_ofs);

        zero_kernel   <<<(BATCH * NCELL) / 256, 256, 0, stream>>>(cnt);
        count_kernel  <<<M / 256, 256, 0, stream>>>(pos, cnt);
        scan_kernel   <<<BATCH, 1024, 0, stream>>>(cnt, off, curp);
        scatter_kernel<<<M / 256, 256, 0, stream>>>(pos, curp, pos4, slotf);
        knnq_kernel   <<<M / 64, 64, 0, stream>>>(pos4, off, idx);

        if (ws_size >= need_big) {
            float* feat1s = (float*)(ws + feat1_ofs);
            feat1s_kernel<<<(M * H_DIM) / 256, 256, 0, stream>>>(pos4, feats, W1, feat1s);
            mlp2s_kernel <<<M / PB, 64, 0, stream>>>(pos4, feats, idx, slotf, feat1s,
                                                     W1, b1, W2, b2, W3, b3, W4, b4, out);
        } else {
            mlp_kernel   <<<M / PB, 64, 0, stream>>>(pos, feats, idx,
                                                     W1, b1, W2, b2, W3, b3, W4, b4, out);
        }
    } else {
        fused_kernel<<<M, NT, 0, stream>>>(pos, feats, W1, b1, W2, b2,
                                           W3, b3, W4, b4, out);
    }
}

// Round 24
// 332.777 us; speedup vs baseline: 1.1183x; 1.1183x over previous
//
#include <hip/hip_runtime.h>
#include <math.h>

#define N_PTS 16384
#define BATCH 2
#define CIN   32
#define H_DIM 128
#define COUT  64
#define KNN   16
#define GC    16                  // grid cells per dimension (bracketed optimum)
#define NCELL (GC * GC * GC)      // 4096
#define CS    (1.0f / GC)
#define PB    4                   // points per MLP block
#define CHUNK 2048

typedef unsigned short ushortT;

__device__ __forceinline__ float gelu_f(float x) {
    float x3 = x * x * x;
    float t  = tanhf(0.7978845608028654f * (x + 0.044715f * x3));
    return 0.5f * x * (1.0f + t);
}
__device__ __forceinline__ float gelu_fast(float x) {
    float z = 1.5957691216057308f * (x + 0.044715f * x * x * x);
    return x / (1.0f + __expf(-z));
}

__device__ __forceinline__ int cellco(float v) {
    int c = (int)(v * (float)GC);
    return c < 0 ? 0 : (c > GC - 1 ? GC - 1 : c);
}

// ---------------- bucket build ----------------
__global__ __launch_bounds__(256)
void zero_kernel(int* __restrict__ cnt) {
    cnt[blockIdx.x * 256 + threadIdx.x] = 0;
}

__global__ __launch_bounds__(256)
void count_kernel(const float* __restrict__ pos, int* __restrict__ cnt) {
    const int t = blockIdx.x * 256 + threadIdx.x;
    const int b = t >> 14;
    float x = pos[(size_t)t * 3 + 0];
    float y = pos[(size_t)t * 3 + 1];
    float z = pos[(size_t)t * 3 + 2];
    int cell = (cellco(z) * GC + cellco(y)) * GC + cellco(x);
    atomicAdd(&cnt[b * NCELL + cell], 1);
}

__global__ __launch_bounds__(1024)
void scan_kernel(const int* __restrict__ cnt, int* __restrict__ off,
                 int* __restrict__ cur) {
    __shared__ int s[1024];
    const int b = blockIdx.x;
    const int t = threadIdx.x;
    const int* c = cnt + b * NCELL;
    const int base = t * 4;
    int v0 = c[base], v1 = c[base + 1], v2 = c[base + 2], v3 = c[base + 3];
    int s01 = v0 + v1, s012 = s01 + v2, tot = s012 + v3;
    s[t] = tot;
    __syncthreads();
    for (int d = 1; d < 1024; d <<= 1) {
        int add = (t >= d) ? s[t - d] : 0;
        __syncthreads();
        s[t] += add;
        __syncthreads();
    }
    int excl = s[t] - tot;
    int* ob = off + b * (NCELL + 1);
    int* cb = cur + b * NCELL;
    ob[base] = excl;            cb[base] = excl;
    ob[base + 1] = excl + v0;   cb[base + 1] = excl + v0;
    ob[base + 2] = excl + s01;  cb[base + 2] = excl + s01;
    ob[base + 3] = excl + s012; cb[base + 3] = excl + s012;
    if (t == 1023) ob[NCELL] = excl + tot;
}

// scatter: also record slot_of[pid] (inverse permutation) for the MLP
__global__ __launch_bounds__(256)
void scatter_kernel(const float* __restrict__ pos, int* __restrict__ cur,
                    float4* __restrict__ pos4, ushortT* __restrict__ slot_of) {
    const int t = blockIdx.x * 256 + threadIdx.x;
    const int b = t >> 14;
    const int pid = t & (N_PTS - 1);
    float x = pos[(size_t)t * 3 + 0];
    float y = pos[(size_t)t * 3 + 1];
    float z = pos[(size_t)t * 3 + 2];
    int cell = (cellco(z) * GC + cellco(y)) * GC + cellco(x);
    int slot = atomicAdd(&cur[b * NCELL + cell], 1);
    pos4[(size_t)b * N_PTS + slot] = make_float4(x, y, z, __int_as_float(pid));
    slot_of[(size_t)b * N_PTS + pid] = (ushortT)slot;
}

// ---- KNN: r17 proven scan + cell-bound pruning (r22, 186us measured).
// A row (or row-end cell) whose min possible d^2 exceeds the current 16th
// (strictly, with 0.99999 conservative factor) provably contains no top-16
// member -> skipping leaves output BIT-IDENTICAL.
__global__ __launch_bounds__(64)
void knnq_kernel(const float4* __restrict__ pos4,
                 const int* __restrict__ off, ushortT* __restrict__ out_idx) {
    __shared__ int soff[NCELL + 1];     // 16.4 KB

    const int tid = threadIdx.x;
    const int t = blockIdx.x * 64 + tid;            // slot id, 0..32767
    const int b = t >> 14;                          // uniform across block
    const int* offb = off + b * (NCELL + 1);
    for (int i = tid; i < NCELL + 1; i += 64) soff[i] = offb[i];

    const float4 Q = pos4[t];                       // coalesced
    const float qx = Q.x, qy = Q.y, qz = Q.z;
    const int pid = __float_as_int(Q.w);
    const int cx = cellco(qx), cy = cellco(qy), cz = cellco(qz);
    const float4* p4b = pos4 + (size_t)b * N_PTS;
    __syncthreads();

    float ld[KNN]; int li[KNN];
#pragma unroll
    for (int p = 0; p < KNN; ++p) { ld[p] = 3.0e38f; li[p] = 0x7fffffff; }
    float t15d = 3.0e38f; int t15i = 0x7fffffff;

    // min |q - cellcoord| along one axis for cell index X (cell = [X*CS,(X+1)*CS))
    auto axmind = [&](int X, float q) {
        float dl = (float)X * CS - q;
        float dh = q - (float)(X + 1) * CS;
        return fmaxf(0.f, fmaxf(dl, dh));
    };

    // scan a contiguous slot range [s,e) with 8-wide batched loads (r12)
    auto scan_range = [&](int s, int e2) {
        for (int u = s; u < e2; u += 8) {
            float4 pg[8];
#pragma unroll
            for (int i = 0; i < 8; ++i) {
                int uu = u + i; uu = uu < e2 - 1 ? uu : e2 - 1;   // clamp
                pg[i] = p4b[uu];
            }
#pragma unroll
            for (int i = 0; i < 8; ++i) {
                if (u + i >= e2) break;
                // exact numpy op order: (dx*dx + dy*dy) + dz*dz, no FMA
                float ddx = __fsub_rn(qx, pg[i].x);
                float ddy = __fsub_rn(qy, pg[i].y);
                float ddz = __fsub_rn(qz, pg[i].z);
                float d = __fadd_rn(__fadd_rn(__fmul_rn(ddx, ddx),
                                              __fmul_rn(ddy, ddy)),
                                    __fmul_rn(ddz, ddz));
                int pj = __float_as_int(pg[i].w);
                if (d < t15d || (d == t15d && pj < t15i)) {
                    float cd = d; int cj = pj;
#pragma unroll
                    for (int p = 0; p < KNN; ++p) {
                        bool sw = (cd < ld[p]) || (cd == ld[p] && cj < li[p]);
                        float td = ld[p]; int ti = li[p];
                        ld[p] = sw ? cd : td; li[p] = sw ? cj : ti;
                        cd = sw ? td : cd;    cj = sw ? ti : cj;
                    }
                    t15d = ld[KNN - 1]; t15i = li[KNN - 1];
                }
            }
        }
    };

    for (int r = 1; r <= GC; ++r) {
        for (int dz = -r; dz <= r; ++dz) {
            const int Z = cz + dz; if ((unsigned)Z >= GC) continue;
            const float fz = axmind(Z, qz);
            for (int dy = -r; dy <= r; ++dy) {
                const int Y = cy + dy; if ((unsigned)Y >= GC) continue;
                const float fy = axmind(Y, qy);
                const float base2 = fy * fy + fz * fz;
                if (base2 * 0.99999f > t15d) continue;   // row provably empty of top-16
                const int rowbase = (Z * GC + Y) * GC;
                const bool fullrow = (r == 1) ||
                    (dz == -r || dz == r || dy == -r || dy == r);
                if (fullrow) {
                    int X0 = cx - r; X0 = X0 < 0 ? 0 : X0;
                    int X1 = cx + r; X1 = X1 > GC - 1 ? GC - 1 : X1;
                    // trim row ends: x-min-dist is monotone toward cx, so this
                    // is an exact per-cell filter on the row.
                    while (X0 < cx) {
                        float fx = axmind(X0, qx);
                        if ((base2 + fx * fx) * 0.99999f > t15d) ++X0; else break;
                    }
                    while (X1 > cx) {
                        float fx = axmind(X1, qx);
                        if ((base2 + fx * fx) * 0.99999f > t15d) --X1; else break;
                    }
                    scan_range(soff[rowbase + X0], soff[rowbase + X1 + 1]);
                } else {
                    const int Xl = cx - r, Xr = cx + r;
                    if (Xl >= 0) {
                        float fx = axmind(Xl, qx);
                        if ((base2 + fx * fx) * 0.99999f <= t15d)
                            scan_range(soff[rowbase + Xl], soff[rowbase + Xl + 1]);
                    }
                    if (Xr <= GC - 1) {
                        float fx = axmind(Xr, qx);
                        if ((base2 + fx * fx) * 0.99999f <= t15d)
                            scan_range(soff[rowbase + Xr], soff[rowbase + Xr + 1]);
                    }
                }
            }
        }
        // conservative termination: any unprocessed point has d^2 >= margin^2
        float mg = 1.0e19f;   // clipped faces -> nothing beyond
        if (cx - r > 0)      mg = fminf(mg, qx - (float)(cx - r) * CS);
        if (cx + r < GC - 1) mg = fminf(mg, (float)(cx + r + 1) * CS - qx);
        if (cy - r > 0)      mg = fminf(mg, qy - (float)(cy - r) * CS);
        if (cy + r < GC - 1) mg = fminf(mg, (float)(cy + r + 1) * CS - qy);
        if (cz - r > 0)      mg = fminf(mg, qz - (float)(cz - r) * CS);
        if (cz + r < GC - 1) mg = fminf(mg, (float)(cz + r + 1) * CS - qz);
        if (t15d < mg * mg * 0.99999f) break;
    }
    ushortT* dst = out_idx + ((size_t)(b << 14) + pid) * KNN;
#pragma unroll
    for (int p = 0; p < KNN; ++p) dst[p] = (ushortT)li[p];
}

// ------- feat1s: SLOT-ordered feat1.  Row s = F[pid(s)] @ W1[0:CIN]. -------
__global__ __launch_bounds__(256)
void feat1s_kernel(const float4* __restrict__ pos4, const float* __restrict__ feats,
                   const float* __restrict__ W1, float* __restrict__ feat1s) {
    const int g = blockIdx.x * 256 + threadIdx.x;    // over M*H_DIM
    const int s = g >> 7;                            // global slot
    const int h = g & 127;
    const int b = s >> 14;
    const int pid = __float_as_int(pos4[s].w);
    const float* fr = feats + ((size_t)b * N_PTS + pid) * CIN;
    float a = 0.f;
#pragma unroll
    for (int c = 0; c < CIN; ++c)
        a += fr[c] * W1[c * H_DIM + h];
    feat1s[(size_t)s * H_DIM + h] = a;
}

// ---- MLP v2s: 4 consecutive SLOTS per block (r21/r22 proven). ----
__global__ __launch_bounds__(64)
void mlp2s_kernel(const float4* __restrict__ pos4, const float* __restrict__ feats,
                  const ushortT* __restrict__ knn_idx, const ushortT* __restrict__ slot_of,
                  const float* __restrict__ feat1s,
                  const float* __restrict__ W1, const float* __restrict__ b1,
                  const float* __restrict__ W2, const float* __restrict__ b2,
                  const float* __restrict__ W3, const float* __restrict__ b3,
                  const float* __restrict__ W4, const float* __restrict__ b4,
                  float* __restrict__ out) {
    __shared__ ushortT sIdx[PB][KNN];         // neighbor SLOTS
    __shared__ int   spid[PB];                // own pids
    __shared__ float sq[PB][3];
    __shared__ __align__(16) float fself[PB][CIN];
    __shared__ float npx[PB][KNN][3];
    __shared__ __align__(16) float gs[PB][H_DIM];
    __shared__ __align__(16) float aggs[PB][COUT];
    __shared__ __align__(16) float hs[PB][H_DIM];

    const int tid = threadIdx.x;            // 0..63
    const int h0 = tid, h1 = tid + 64;
    const int i0 = blockIdx.x * PB;         // global slot base
    const int b  = i0 >> 14;
    const size_t bofs = (size_t)b * N_PTS;

    if (tid < PB) {
        float4 P = pos4[i0 + tid];
        sq[tid][0] = P.x; sq[tid][1] = P.y; sq[tid][2] = P.z;
        spid[tid] = __float_as_int(P.w);
    }
    __syncthreads();     // spid/sq ready
    for (int e = tid; e < PB * KNN; e += 64) {
        int p = e >> 4, k = e & 15;
        int npid = knn_idx[(bofs + spid[p]) * KNN + k];
        sIdx[p][k] = slot_of[bofs + npid];
    }
    for (int e = tid; e < PB * CIN; e += 64)
        fself[e >> 5][e & 31] = feats[(bofs + spid[e >> 5]) * CIN + (e & 31)];
    __syncthreads();     // sIdx ready
    for (int e = tid; e < PB * KNN; e += 64) {
        int p = e >> 4, k = e & 15;
        float4 P = pos4[bofs + sIdx[p][k]];
        npx[p][k][0] = P.x; npx[p][k][1] = P.y; npx[p][k][2] = P.z;
    }

    const float w0A = W1[(2 * CIN + 0) * H_DIM + h0], w0B = W1[(2 * CIN + 0) * H_DIM + h1];
    const float w1A = W1[(2 * CIN + 1) * H_DIM + h0], w1B = W1[(2 * CIN + 1) * H_DIM + h1];
    const float w2A = W1[(2 * CIN + 2) * H_DIM + h0], w2B = W1[(2 * CIN + 2) * H_DIM + h1];
    float bA[PB], bB[PB];
#pragma unroll
    for (int p = 0; p < PB; ++p) { bA[p] = b1[h0]; bB[p] = b1[h1]; }
    __syncthreads();   // npx/fself ready
#pragma unroll
    for (int c = 0; c < CIN; ++c) {
        float wA = W1[(CIN + c) * H_DIM + h0];
        float wB = W1[(CIN + c) * H_DIM + h1];
#pragma unroll
        for (int p = 0; p < PB; ++p) {
            bA[p] += fself[p][c] * wA;
            bB[p] += fself[p][c] * wB;
        }
    }

    float accA[PB] = {0.f, 0.f, 0.f, 0.f};
    float accB[PB] = {0.f, 0.f, 0.f, 0.f};
    for (int k = 0; k < KNN; ++k) {
#pragma unroll
        for (int p = 0; p < PB; ++p) {
            const float* fr = feat1s + ((size_t)bofs + sIdx[p][k]) * H_DIM;
            float rx = npx[p][k][0] - sq[p][0];
            float ry = npx[p][k][1] - sq[p][1];
            float rz = npx[p][k][2] - sq[p][2];
            float uA = bA[p] + fr[h0] + rx * w0A + ry * w1A + rz * w2A;
            float uB = bB[p] + fr[h1] + rx * w0B + ry * w1B + rz * w2B;
            accA[p] += gelu_fast(uA);
            accB[p] += gelu_fast(uB);
        }
    }
#pragma unroll
    for (int p = 0; p < PB; ++p) {
        gs[p][h0] = accA[p] * (1.0f / KNN);
        gs[p][h1] = accB[p] * (1.0f / KNN);
    }
    __syncthreads();

    float a2[PB];
#pragma unroll
    for (int p = 0; p < PB; ++p) a2[p] = b2[h0];
    for (int c4 = 0; c4 < H_DIM / 4; ++c4) {
        float wx = W2[(4 * c4 + 0) * COUT + h0];
        float wy = W2[(4 * c4 + 1) * COUT + h0];
        float wz = W2[(4 * c4 + 2) * COUT + h0];
        float ww = W2[(4 * c4 + 3) * COUT + h0];
#pragma unroll
        for (int p = 0; p < PB; ++p) {
            float4 g = ((const float4*)gs[p])[c4];
            a2[p] += g.x * wx + g.y * wy + g.z * wz + g.w * ww;
        }
    }
#pragma unroll
    for (int p = 0; p < PB; ++p) aggs[p][h0] = a2[p];
    __syncthreads();

    float a3A[PB], a3B[PB];
#pragma unroll
    for (int p = 0; p < PB; ++p) { a3A[p] = b3[h0]; a3B[p] = b3[h1]; }
    for (int c4 = 0; c4 < COUT / 4; ++c4) {
        float wxA = W3[(4 * c4 + 0) * H_DIM + h0], wxB = W3[(4 * c4 + 0) * H_DIM + h1];
        float wyA = W3[(4 * c4 + 1) * H_DIM + h0], wyB = W3[(4 * c4 + 1) * H_DIM + h1];
        float wzA = W3[(4 * c4 + 2) * H_DIM + h0], wzB = W3[(4 * c4 + 2) * H_DIM + h1];
        float wwA = W3[(4 * c4 + 3) * H_DIM + h0], wwB = W3[(4 * c4 + 3) * H_DIM + h1];
#pragma unroll
        for (int p = 0; p < PB; ++p) {
            float4 g = ((const float4*)aggs[p])[c4];
            a3A[p] += g.x * wxA + g.y * wyA + g.z * wzA + g.w * wwA;
            a3B[p] += g.x * wxB + g.y * wyB + g.z * wzB + g.w * wwB;
        }
    }
#pragma unroll
    for (int p = 0; p < PB; ++p) {
        hs[p][h0] = gelu_fast(a3A[p]);
        hs[p][h1] = gelu_fast(a3B[p]);
    }
    __syncthreads();

    float o4[PB];
#pragma unroll
    for (int p = 0; p < PB; ++p) o4[p] = b4[h0];
    for (int c4 = 0; c4 < H_DIM / 4; ++c4) {
        float wx = W4[(4 * c4 + 0) * COUT + h0];
        float wy = W4[(4 * c4 + 1) * COUT + h0];
        float wz = W4[(4 * c4 + 2) * COUT + h0];
        float ww = W4[(4 * c4 + 3) * COUT + h0];
#pragma unroll
        for (int p = 0; p < PB; ++p) {
            float4 v = ((const float4*)hs[p])[c4];
            o4[p] += v.x * wx + v.y * wy + v.z * wz + v.w * ww;
        }
    }
#pragma unroll
    for (int p = 0; p < PB; ++p)
        out[((size_t)bofs + spid[p]) * COUT + h0] = o4[p];
}

// ---------- MLP v1 (round-8, proven): used when ws too small for feat1 -------
__global__ __launch_bounds__(64)
void mlp_kernel(const float* __restrict__ pos, const float* __restrict__ feats,
                const ushortT* __restrict__ knn_idx,
                const float* __restrict__ W1, const float* __restrict__ b1,
                const float* __restrict__ W2, const float* __restrict__ b2,
                const float* __restrict__ W3, const float* __restrict__ b3,
                const float* __restrict__ W4, const float* __restrict__ b4,
                float* __restrict__ out) {
    __shared__ ushortT sIdx[PB][KNN];
    __shared__ float sq[PB][3];
    __shared__ __align__(16) float fself[PB][CIN];
    __shared__ float npx[PB][KNN][3];
    __shared__ __align__(16) float nf[PB][KNN][CIN];
    __shared__ __align__(16) float gs[PB][H_DIM];
    __shared__ __align__(16) float aggs[PB][COUT];
    __shared__ __align__(16) float hs[PB][H_DIM];

    const int tid = threadIdx.x;
    const int h0 = tid, h1 = tid + 64;
    const int i0 = blockIdx.x * PB;
    const size_t bofs = (size_t)(i0 >> 14) * N_PTS;

    for (int e = tid; e < PB * KNN; e += 64)
        sIdx[e >> 4][e & 15] = knn_idx[(size_t)(i0 + (e >> 4)) * KNN + (e & 15)];
    for (int e = tid; e < PB * 3; e += 64)
        sq[e / 3][e % 3] = pos[(size_t)(i0 + e / 3) * 3 + (e % 3)];
    for (int e = tid; e < PB * CIN; e += 64)
        fself[e >> 5][e & 31] = feats[(size_t)(i0 + (e >> 5)) * CIN + (e & 31)];
    __syncthreads();
    for (int e = tid; e < PB * KNN * CIN; e += 64) {
        int p = e >> 9, k = (e >> 5) & 15, c = e & 31;
        nf[p][k][c] = feats[(bofs + sIdx[p][k]) * CIN + c];
    }
    for (int e = tid; e < PB * KNN * 3; e += 64) {
        int p = e / (KNN * 3), r = e % (KNN * 3), k = r / 3, c = r % 3;
        npx[p][k][c] = pos[(bofs + sIdx[p][k]) * 3 + c];
    }

    float w1rA[CIN], w1rB[CIN];
#pragma unroll
    for (int c = 0; c < CIN; ++c) {
        w1rA[c] = W1[c * H_DIM + h0];
        w1rB[c] = W1[c * H_DIM + h1];
    }
    const float w0A = W1[(2 * CIN + 0) * H_DIM + h0], w0B = W1[(2 * CIN + 0) * H_DIM + h1];
    const float w1A = W1[(2 * CIN + 1) * H_DIM + h0], w1B = W1[(2 * CIN + 1) * H_DIM + h1];
    const float w2A = W1[(2 * CIN + 2) * H_DIM + h0], w2B = W1[(2 * CIN + 2) * H_DIM + h1];
    float bA[PB], bB[PB];
#pragma unroll
    for (int p = 0; p < PB; ++p) { bA[p] = b1[h0]; bB[p] = b1[h1]; }
    __syncthreads();
#pragma unroll
    for (int c = 0; c < CIN; ++c) {
        float wA = W1[(CIN + c) * H_DIM + h0];
        float wB = W1[(CIN + c) * H_DIM + h1];
#pragma unroll
        for (int p = 0; p < PB; ++p) {
            bA[p] += fself[p][c] * wA;
            bB[p] += fself[p][c] * wB;
        }
    }

    float accA[PB] = {0.f, 0.f, 0.f, 0.f};
    float accB[PB] = {0.f, 0.f, 0.f, 0.f};
    for (int k = 0; k < KNN; ++k) {
#pragma unroll
        for (int p = 0; p < PB; ++p) {
            float rx = npx[p][k][0] - sq[p][0];
            float ry = npx[p][k][1] - sq[p][1];
            float rz = npx[p][k][2] - sq[p][2];
            float uA = bA[p] + rx * w0A + ry * w1A + rz * w2A;
            float uB = bB[p] + rx * w0B + ry * w1B + rz * w2B;
            const float4* nf4 = (const float4*)nf[p][k];
#pragma unroll
            for (int c4 = 0; c4 < CIN / 4; ++c4) {
                float4 v = nf4[c4];
                uA += v.x * w1rA[4 * c4] + v.y * w1rA[4 * c4 + 1]
                    + v.z * w1rA[4 * c4 + 2] + v.w * w1rA[4 * c4 + 3];
                uB += v.x * w1rB[4 * c4] + v.y * w1rB[4 * c4 + 1]
                    + v.z * w1rB[4 * c4 + 2] + v.w * w1rB[4 * c4 + 3];
            }
            accA[p] += gelu_f(uA);
            accB[p] += gelu_f(uB);
        }
    }
#pragma unroll
    for (int p = 0; p < PB; ++p) {
        gs[p][h0] = accA[p] * (1.0f / KNN);
        gs[p][h1] = accB[p] * (1.0f / KNN);
    }
    __syncthreads();

    float a2[PB];
#pragma unroll
    for (int p = 0; p < PB; ++p) a2[p] = b2[h0];
    for (int c4 = 0; c4 < H_DIM / 4; ++c4) {
        float wx = W2[(4 * c4 + 0) * COUT + h0];
        float wy = W2[(4 * c4 + 1) * COUT + h0];
        float wz = W2[(4 * c4 + 2) * COUT + h0];
        float ww = W2[(4 * c4 + 3) * COUT + h0];
#pragma unroll
        for (int p = 0; p < PB; ++p) {
            float4 g = ((const float4*)gs[p])[c4];
            a2[p] += g.x * wx + g.y * wy + g.z * wz + g.w * ww;
        }
    }
#pragma unroll
    for (int p = 0; p < PB; ++p) aggs[p][h0] = a2[p];
    __syncthreads();

    float a3A[PB], a3B[PB];
#pragma unroll
    for (int p = 0; p < PB; ++p) { a3A[p] = b3[h0]; a3B[p] = b3[h1]; }
    for (int c4 = 0; c4 < COUT / 4; ++c4) {
        float wxA = W3[(4 * c4 + 0) * H_DIM + h0], wxB = W3[(4 * c4 + 0) * H_DIM + h1];
        float wyA = W3[(4 * c4 + 1) * H_DIM + h0], wyB = W3[(4 * c4 + 1) * H_DIM + h1];
        float wzA = W3[(4 * c4 + 2) * H_DIM + h0], wzB = W3[(4 * c4 + 2) * H_DIM + h1];
        float wwA = W3[(4 * c4 + 3) * H_DIM + h0], wwB = W3[(4 * c4 + 3) * H_DIM + h1];
#pragma unroll
        for (int p = 0; p < PB; ++p) {
            float4 g = ((const float4*)aggs[p])[c4];
            a3A[p] += g.x * wxA + g.y * wyA + g.z * wzA + g.w * wwA;
            a3B[p] += g.x * wxB + g.y * wyB + g.z * wzB + g.w * wwB;
        }
    }
#pragma unroll
    for (int p = 0; p < PB; ++p) {
        hs[p][h0] = gelu_f(a3A[p]);
        hs[p][h1] = gelu_f(a3B[p]);
    }
    __syncthreads();

    float o4[PB];
#pragma unroll
    for (int p = 0; p < PB; ++p) o4[p] = b4[h0];
    for (int c4 = 0; c4 < H_DIM / 4; ++c4) {
        float wx = W4[(4 * c4 + 0) * COUT + h0];
        float wy = W4[(4 * c4 + 1) * COUT + h0];
        float wz = W4[(4 * c4 + 2) * COUT + h0];
        float ww = W4[(4 * c4 + 3) * COUT + h0];
#pragma unroll
        for (int p = 0; p < PB; ++p) {
            float4 v = ((const float4*)hs[p])[c4];
            o4[p] += v.x * wx + v.y * wy + v.z * wz + v.w * ww;
        }
    }
#pragma unroll
    for (int p = 0; p < PB; ++p)
        out[(size_t)(i0 + p) * COUT + h0] = o4[p];
}

// =============== FALLBACK: round-6 fused kernel (proven passing) =============
#define NT    128
#define LP    17
__global__ __launch_bounds__(NT)
void fused_kernel(const float* __restrict__ pos, const float* __restrict__ feats,
                  const float* __restrict__ W1, const float* __restrict__ b1,
                  const float* __restrict__ W2, const float* __restrict__ b2,
                  const float* __restrict__ W3, const float* __restrict__ b3,
                  const float* __restrict__ W4, const float* __restrict__ b4,
                  float* __restrict__ out) {
    __shared__ float sx[CHUNK], sy[CHUNK], sz[CHUNK];
    __shared__ float ld0[NT * LP]; __shared__ int li0[NT * LP];
    __shared__ float ld1[NT * LP]; __shared__ int li1[NT * LP];
    __shared__ int   sIdx[KNN];
    __shared__ float npx[KNN][3];
    __shared__ float nf[KNN][CIN];
    __shared__ float fself[CIN];
    __shared__ float gs[H_DIM];
    __shared__ float aggs[COUT];
    __shared__ float hs[H_DIM];

    const int i   = blockIdx.x;
    const int b   = i >> 14;
    const int tid = threadIdx.x;
    const float* posb = pos + (size_t)b * N_PTS * 3;

    const float qx = pos[(size_t)i * 3 + 0];
    const float qy = pos[(size_t)i * 3 + 1];
    const float qz = pos[(size_t)i * 3 + 2];

    const int base = tid * LP;
    for (int s = 0; s < KNN; ++s) { ld0[base + s] = 3.0e38f; li0[base + s] = 0x7fffffff; }
    float taild = 3.0e38f;

    for (int cbase = 0; cbase < N_PTS; cbase += CHUNK) {
        __syncthreads();
        for (int t = tid; t < CHUNK * 3; t += NT) {
            float v = posb[(size_t)cbase * 3 + t];
            int c = t % 3, r = t / 3;
            (c == 0 ? sx : (c == 1 ? sy : sz))[r] = v;
        }
        __syncthreads();
        for (int r = tid; r < CHUNK; r += NT) {
            float dx = __fsub_rn(qx, sx[r]);
            float dy = __fsub_rn(qy, sy[r]);
            float dz = __fsub_rn(qz, sz[r]);
            float d  = __fadd_rn(__fadd_rn(__fmul_rn(dx, dx), __fmul_rn(dy, dy)),
                                 __fmul_rn(dz, dz));
            const int j = cbase + r;
            if (d < taild) {
                int p = KNN - 1;
                while (p > 0) {
                    float pd = ld0[base + p - 1];
                    if (!(pd > d)) break;
                    ld0[base + p] = pd;
                    li0[base + p] = li0[base + p - 1];
                    --p;
                }
                ld0[base + p] = d;
                li0[base + p] = j;
                taild = ld0[base + KNN - 1];
            }
        }
    }

    int cur = 0;
    for (int s = 1; s < NT; s <<= 1) {
        __syncthreads();
        if ((tid & (2 * s - 1)) == 0) {
            const float* cd  = cur ? ld1 : ld0;
            const int*   cix = cur ? li1 : li0;
            float* nd  = cur ? ld0 : ld1;
            int*   nix = cur ? li0 : li1;
            const int A = tid * LP, B = (tid + s) * LP, O = tid * LP;
            int a = 0, bb = 0;
            for (int o = 0; o < KNN; ++o) {
                float da = cd[A + a], db = cd[B + bb];
                int   ia = cix[A + a], ib = cix[B + bb];
                bool tA = (da < db) || (da == db && ia < ib);
                nd[O + o]  = tA ? da : db;
                nix[O + o] = tA ? ia : ib;
                a += tA ? 1 : 0; bb += tA ? 0 : 1;
            }
        }
        cur ^= 1;
    }
    __syncthreads();
    {
        const int* fli = cur ? li1 : li0;
        if (tid < KNN) sIdx[tid] = fli[tid];
        if (tid < CIN) fself[tid] = feats[(size_t)i * CIN + tid];
    }
    __syncthreads();

    for (int e = tid; e < KNN * CIN; e += NT) {
        int k = e >> 5, c = e & 31;
        nf[k][c] = feats[((size_t)b * N_PTS + sIdx[k]) * CIN + c];
    }
    if (tid < KNN * 3) {
        int k = tid / 3, c = tid % 3;
        npx[k][c] = posb[sIdx[k] * 3 + c];
    }
    const int h = tid;
    float w1r[CIN];
#pragma unroll
    for (int c = 0; c < CIN; ++c) w1r[c] = W1[c * H_DIM + h];
    float baseh = b1[h];
    const float w0 = W1[(2 * CIN + 0) * H_DIM + h];
    const float w1 = W1[(2 * CIN + 1) * H_DIM + h];
    const float w2 = W1[(2 * CIN + 2) * H_DIM + h];
#pragma unroll
    for (int c = 0; c < CIN; ++c)
        baseh += fself[c] * W1[(CIN + c) * H_DIM + h];
    __syncthreads();

    float acc = 0.f;
    for (int k = 0; k < KNN; ++k) {
        float u = baseh
                + (npx[k][0] - qx) * w0
                + (npx[k][1] - qy) * w1
                + (npx[k][2] - qz) * w2;
#pragma unroll
        for (int c = 0; c < CIN; ++c)
            u += nf[k][c] * w1r[c];
        acc += gelu_f(u);
    }
    gs[h] = acc * (1.0f / KNN);
    __syncthreads();

    if (h < COUT) {
        float a = b2[h];
#pragma unroll
        for (int t2 = 0; t2 < H_DIM; ++t2)
            a += gs[t2] * W2[t2 * COUT + h];
        aggs[h] = a;
    }
    __syncthreads();

    float a3 = b3[h];
#pragma unroll
    for (int c = 0; c < COUT; ++c)
        a3 += aggs[c] * W3[c * H_DIM + h];
    hs[h] = gelu_f(a3);
    __syncthreads();
    if (h < COUT) {
        float o = b4[h];
#pragma unroll
        for (int t2 = 0; t2 < H_DIM; ++t2)
            o += hs[t2] * W4[t2 * COUT + h];
        out[(size_t)i * COUT + h] = o;
    }
}

extern "C" void kernel_launch(void* const* d_in, const int* in_sizes, int n_in,
                              void* d_out, int out_size, void* d_ws, size_t ws_size,
                              hipStream_t stream) {
    const float* pos   = (const float*)d_in[0];
    const float* feats = (const float*)d_in[1];
    const float* W1    = (const float*)d_in[2];
    const float* b1    = (const float*)d_in[3];
    const float* W2    = (const float*)d_in[4];
    const float* b2    = (const float*)d_in[5];
    const float* W3    = (const float*)d_in[6];
    const float* b3    = (const float*)d_in[7];
    const float* W4    = (const float*)d_in[8];
    const float* b4    = (const float*)d_in[9];
    float* out = (float*)d_out;

    const int M = BATCH * N_PTS;   // 32768

    // ws layout (GC=16):
    //   [0,1MB)              idx     ushort [32768*16]
    //   [1MB,1.5MB)          pos4    float4 [32768]
    //   [1.5MB,+32KB)        cnt     int [2*4096]
    //   [+32KB,+65KB)        off     int [2*4097]
    //   [+65KB,+97KB)        cur     int [2*4096]
    //   [+97KB,+161KB)       slot_of ushort [32768]
    //   [2MB,18MB)           feat1s  f32 [32768*128]    (only if ws >= 18MB)
    char* ws = (char*)d_ws;
    const size_t need_small = (size_t)1536 * 1024 + 161 * 1024;
    const size_t need_big   = (size_t)18 * 1024 * 1024;

    if (ws_size >= need_small && d_ws != nullptr) {
        ushortT* idx   = (ushortT*)ws;
        float4*  pos4  = (float4*)(ws + (size_t)1024 * 1024);
        int*     cnt   = (int*)(ws + (size_t)1536 * 1024);
        int*     off   = (int*)(ws + (size_t)1536 * 1024 + 32 * 1024);
        int*     curp  = (int*)(ws + (size_t)1536 * 1024 + 65 * 1024);
        ushortT* slotf = (ushortT*)(ws + (size_t)1536 * 1024 + 97 * 1024);

        zero_kernel   <<<(BATCH * NCELL) / 256, 256, 0, stream>>>(cnt);
        count_kernel  <<<M / 256, 256, 0, stream>>>(pos, cnt);
        scan_kernel   <<<BATCH, 1024, 0, stream>>>(cnt, off, curp);
        scatter_kernel<<<M / 256, 256, 0, stream>>>(pos, curp, pos4, slotf);
        knnq_kernel   <<<M / 64, 64, 0, stream>>>(pos4, off, idx);

        if (ws_size >= need_big) {
            float* feat1s = (float*)(ws + (size_t)2 * 1024 * 1024);
            feat1s_kernel<<<(M * H_DIM) / 256, 256, 0, stream>>>(pos4, feats, W1, feat1s);
            mlp2s_kernel <<<M / PB, 64, 0, stream>>>(pos4, feats, idx, slotf, feat1s,
                                                     W1, b1, W2, b2, W3, b3, W4, b4, out);
        } else {
            mlp_kernel   <<<M / PB, 64, 0, stream>>>(pos, feats, idx,
                                                     W1, b1, W2, b2, W3, b3, W4, b4, out);
        }
    } else {
        fused_kernel<<<M, NT, 0, stream>>>(pos, feats, W1, b1, W2, b2,
                                           W3, b3, W4, b4, out);
    }
}